// Round 7
// baseline (908.301 us; speedup 1.0000x reference)
//
#include <hip/hip_runtime.h>
#include <hip/hip_bf16.h>

#define B_   128
#define S_   512
#define H_   128
#define G_   512   // 4*H
#define EMB_ 128
#define NL_  9
#define CPW_ 2     // chains per workgroup

typedef __attribute__((ext_vector_type(8))) short bf16x8;
typedef __attribute__((ext_vector_type(4))) float f32x4;

// padded fragment slot: chunk stride 17 (16 rows + 1 pad)
#define FRAG(c, r) ((c) * 17 + (r))
// chunks: 0..15 xbuf0 | 16..31 xbuf1 | 32..47 hbuf0 | 48..63 hbuf1

// raw barrier: LDS fence only — vmem ops (prefetch loads, emission stores)
// stay in flight across it. "memory" clobber pins LDS op ordering.
__device__ __forceinline__ void wg_bar() {
    asm volatile("s_waitcnt lgkmcnt(0)\n\ts_barrier" ::: "memory");
}

__device__ __forceinline__ float bfbits2f(short s) {
    unsigned int u = ((unsigned int)(unsigned short)s) << 16;
    return __builtin_bit_cast(float, u);
}
__device__ __forceinline__ short f2bf(float f) {
    unsigned int u = __builtin_bit_cast(unsigned int, f);
    u += 0x7FFFu + ((u >> 16) & 1u);
    return (short)(u >> 16);
}
__device__ __forceinline__ float sigm(float x) {
    return __builtin_amdgcn_rcpf(1.f + exp2f(-1.4426950408889634f * x));
}
__device__ __forceinline__ float tanh_(float x) {
    return 1.f - 2.f * __builtin_amdgcn_rcpf(1.f + exp2f(2.8853900817779268f * x));
}

// ---------------------------------------------------------------------------
// Fused LSTM + emissions, ONE barrier per step.
// 128 wgs (64/dir), 2 chains, 512 thr (8 waves).
// Column map: wave w, tile nt -> col n = w*16 + n16 + nt*128, so a quad-0
// lane holds i,f,g,o (nt=0..3) for hidden position j = w*16+n16, chains =
// D rows 0,1 -> LSTM update is IN-LANE (no gates LDS round-trip).
// h double-buffered in LDS; x double-buffered, staged by wave 7 with a
// 3-deep register pipeline. Emissions by waves 1-3 (fire-and-forget stores).
// ---------------------------------------------------------------------------
__global__ __launch_bounds__(512, 2)
void lstm_em_kernel(const int* __restrict__ seq, const float* __restrict__ emb,
                    const float* __restrict__ w_ih_f, const float* __restrict__ w_hh_f,
                    const float* __restrict__ b_ih_f, const float* __restrict__ b_hh_f,
                    const float* __restrict__ w_ih_b, const float* __restrict__ w_hh_b,
                    const float* __restrict__ b_ih_b, const float* __restrict__ b_hh_b,
                    const float* __restrict__ w_out,
                    float* __restrict__ em_f, float* __restrict__ em_b)
{
    __shared__ bf16x8 ldsA[64 * 17];        // 17408 B
    __shared__ int    ldsSeq[CPW_ * S_];    // 4 KB [chain][global t]

    const int tid  = threadIdx.x;
    const int wv   = tid >> 6;
    const int n16  = tid & 15;
    const int quad = (tid & 63) >> 4;
    const int dir  = blockIdx.x >> 6;
    const int brow0 = (blockIdx.x & 63) * CPW_;

    const float* wih = dir ? w_ih_b : w_ih_f;
    const float* whh = dir ? w_hh_b : w_hh_f;
    const float* bih = dir ? b_ih_b : b_ih_f;
    const float* bhh = dir ? b_hh_b : b_hh_f;
    float* emdir = dir ? em_b : em_f;

    // B fragments + bias, col n = wv*16 + n16 + nt*128 (nt: 0=i 1=f 2=g 3=o)
    bf16x8 bfrag[4][8];
    float  bias[4];
#pragma unroll
    for (int nt = 0; nt < 4; nt++) {
        int n = wv * 16 + n16 + nt * 128;
        bias[nt] = bih[n] + bhh[n];
#pragma unroll
        for (int ks = 0; ks < 8; ks++) {
            const float* p = (ks < 4) ? (wih + n * EMB_ + ks * 32 + quad * 8)
                                      : (whh + n * H_ + (ks - 4) * 32 + quad * 8);
            bf16x8 fr;
#pragma unroll
            for (int j = 0; j < 8; j++) fr[j] = f2bf(p[j]);
            bfrag[nt][ks] = fr;
        }
    }

    // emission lanes: waves 1-3, 8 lanes per (chain, label)
    const int eidx = tid - 64;
    const int eg = eidx >> 3, esub = eidx & 7;
    const bool edo = (tid >= 64) && (eg < 2 * NL_);
    const int ec = edo ? (eg / NL_) : 0;
    const int el = edo ? (eg % NL_) : 0;
    float wem[16];
    if (edo) {
#pragma unroll
        for (int k = 0; k < 16; k++)
            wem[k] = w_out[el * 256 + dir * 128 + esub * 16 + k];
    }

    // zero both h buffers (chunks 32..63)
    {   bf16x8 z = {0,0,0,0,0,0,0,0};
        for (int i = tid; i < 32 * 17; i += 512) ldsA[32 * 17 + i] = z;
    }
    ldsSeq[tid]       = seq[brow0 * S_ + tid];
    ldsSeq[tid + 512] = seq[(brow0 + 1) * S_ + tid];

    // wave 7: preload x_0 -> xbuf0, x_1 -> rx[0], x_2 -> rx[1]
    const int xch  = (tid & 63) >> 5;
    const int part = tid & 31;
    float4 rx[2];
    if (wv == 7) {
        int t0 = dir ? (S_ - 1) : 0;
        int t1 = dir ? (S_ - 2) : 1;
        int t2 = dir ? (S_ - 3) : 2;
        const int* sq = seq + (brow0 + xch) * S_;
        float4 r0 = *(const float4*)(emb + (size_t)sq[t0] * EMB_ + part * 4);
        rx[0]     = *(const float4*)(emb + (size_t)sq[t1] * EMB_ + part * 4);
        rx[1]     = *(const float4*)(emb + (size_t)sq[t2] * EMB_ + part * 4);
        short4 s;
        s.x = f2bf(r0.x); s.y = f2bf(r0.y); s.z = f2bf(r0.z); s.w = f2bf(r0.w);
        *(short4*)((short*)ldsA + FRAG(part >> 1, xch) * 8 + (part & 1) * 4) = s;
    }

    float c0 = 0.f, c1 = 0.f;                // cell states (quad-0 lanes)
    const int upj = wv * 16 + n16;           // hidden position for update
    wg_bar();

    for (int t = 0; t < S_; t++) {
        const int xb = (t & 1) * 16;              // x read buffer
        const int xw = 16 - xb;                   // x write buffer (x_{t+1})
        const int rb = 32 + ((t + 1) & 1) * 16;   // h read buffer (h_{t-1})
        const int wb = 32 + (t & 1) * 16;         // h write buffer (h_t)

        if (wv == 7) {
            if (t < S_ - 1) {                     // write x_{t+1} (in rx[t&1])
                float4 r = rx[t & 1];
                short4 s;
                s.x = f2bf(r.x); s.y = f2bf(r.y); s.z = f2bf(r.z); s.w = f2bf(r.w);
                *(short4*)((short*)ldsA + FRAG(xw + (part >> 1), xch) * 8 + (part & 1) * 4) = s;
            }
            if (t < S_ - 3) {                     // issue load of x_{t+3}
                int tt3 = dir ? (S_ - 4 - t) : (t + 3);
                int tok = ldsSeq[xch * S_ + tt3];
                rx[t & 1] = *(const float4*)(emb + (size_t)tok * EMB_ + part * 4);
            }
        }
        if (edo && t > 0) {                       // emission for h_{t-1}
            int ttp = dir ? (S_ - t) : (t - 1);
            bf16x8 h0 = ldsA[FRAG(rb + esub * 2, ec)];
            bf16x8 h1 = ldsA[FRAG(rb + esub * 2 + 1, ec)];
            float d = 0.f;
#pragma unroll
            for (int k = 0; k < 8; k++) d += bfbits2f(h0[k]) * wem[k];
#pragma unroll
            for (int k = 0; k < 8; k++) d += bfbits2f(h1[k]) * wem[8 + k];
            d += __shfl_down(d, 4, 8);
            d += __shfl_down(d, 2, 8);
            d += __shfl_down(d, 1, 8);
            if (esub == 0)
                emdir[((size_t)(brow0 + ec) * S_ + ttp) * NL_ + el] = d;
        }

        // MFMA: gates = [x_t | h_{t-1}] @ Wcat^T, bias folded into C-init
        bf16x8 af[8];
#pragma unroll
        for (int ks = 0; ks < 4; ks++) af[ks]     = ldsA[FRAG(xb + ks * 4 + quad, n16)];
#pragma unroll
        for (int ks = 0; ks < 4; ks++) af[4 + ks] = ldsA[FRAG(rb + ks * 4 + quad, n16)];
        f32x4 acc[4];
#pragma unroll
        for (int nt = 0; nt < 4; nt++) {
            f32x4 a = {bias[nt], bias[nt], bias[nt], bias[nt]};
            acc[nt] = a;
        }
#pragma unroll
        for (int ks = 0; ks < 8; ks++)
#pragma unroll
            for (int nt = 0; nt < 4; nt++)
                acc[nt] = __builtin_amdgcn_mfma_f32_16x16x32_bf16(af[ks], bfrag[nt][ks], acc[nt], 0, 0, 0);

        // in-lane LSTM update (quad-0: rows 0,1 = chains 0,1)
        if (quad == 0) {
            c0 = sigm(acc[1][0]) * c0 + sigm(acc[0][0]) * tanh_(acc[2][0]);
            float h0v = sigm(acc[3][0]) * tanh_(c0);
            c1 = sigm(acc[1][1]) * c1 + sigm(acc[0][1]) * tanh_(acc[2][1]);
            float h1v = sigm(acc[3][1]) * tanh_(c1);
            short* hp = (short*)ldsA;
            hp[FRAG(wb + (upj >> 3), 0) * 8 + (upj & 7)] = f2bf(h0v);
            hp[FRAG(wb + (upj >> 3), 1) * 8 + (upj & 7)] = f2bf(h1v);
        }
        wg_bar();
    }

    // final emission: h_{S-1} in buffer (S-1)&1 = 1 -> chunks 48..63
    if (edo) {
        int ttp = dir ? 0 : (S_ - 1);
        bf16x8 h0 = ldsA[FRAG(48 + esub * 2, ec)];
        bf16x8 h1 = ldsA[FRAG(48 + esub * 2 + 1, ec)];
        float d = 0.f;
#pragma unroll
        for (int k = 0; k < 8; k++) d += bfbits2f(h0[k]) * wem[k];
#pragma unroll
        for (int k = 0; k < 8; k++) d += bfbits2f(h1[k]) * wem[8 + k];
        d += __shfl_down(d, 4, 8);
        d += __shfl_down(d, 2, 8);
        d += __shfl_down(d, 1, 8);
        if (esub == 0)
            emdir[((size_t)(brow0 + ec) * S_ + ttp) * NL_ + el] = d;
    }
}

// ---------------------------------------------------------------------------
// CRF: one wg (256 thr) per batch. Stage em (f+b+bias), trans, mask into LDS
// with coalesced loads; then parallel numerator + wave-0 sequential scan over
// len-1 steps reading LDS only.
// ---------------------------------------------------------------------------
__global__ __launch_bounds__(256, 2)
void crf_kernel(const int* __restrict__ seq, const int* __restrict__ lab,
                const float* __restrict__ em_f, const float* __restrict__ em_b,
                const float* __restrict__ b_out,
                const float* __restrict__ start_t, const float* __restrict__ end_t,
                const float* __restrict__ trans, float* __restrict__ partial)
{
    __shared__ float emS[S_ * NL_];      // 18432 B
    __shared__ float transS[NL_ * NL_];
    __shared__ float stS[NL_], enS[NL_];
    __shared__ float red[256];
    __shared__ int   redi[256];

    const int b = blockIdx.x, tid = threadIdx.x;
    const size_t base = (size_t)b * S_ * NL_;
    const float L2E = 1.4426950408889634f, LN2 = 0.6931471805599453f;

    for (int q = tid; q < S_ * NL_; q += 256) {
        int jq = q % NL_;
        emS[q] = em_f[base + q] + em_b[base + q] + b_out[jq];
    }
    if (tid < NL_ * NL_) transS[tid] = trans[tid];
    if (tid < NL_) { stS[tid] = start_t[tid]; enS[tid] = end_t[tid]; }
    int cnt = (seq[b * S_ + tid] != 0) + (seq[b * S_ + tid + 256] != 0);
    redi[tid] = cnt;
    __syncthreads();
    for (int off = 128; off; off >>= 1) {
        if (tid < off) redi[tid] += redi[tid + off];
        __syncthreads();
    }
    const int len = redi[0];   // all t < len unmasked, t >= len masked

    // numerator partials (t = 1..len-1)
    float np = 0.f;
    for (int t = tid; t < S_; t += 256) {
        if (t >= 1 && t < len) {
            int lp = lab[b * S_ + t - 1], lc = lab[b * S_ + t];
            np += transS[lp * NL_ + lc] + emS[t * NL_ + lc];
        }
    }
    red[tid] = np;
    __syncthreads();
    for (int off = 128; off; off >>= 1) {
        if (tid < off) red[tid] += red[tid + off];
        __syncthreads();
    }

    // wave 0: sequential 9-state logsumexp scan over LDS
    if (tid < 64) {
        const int j = (tid < NL_) ? tid : (NL_ - 1);
        float Tc[NL_];
#pragma unroll
        for (int i = 0; i < NL_; i++) Tc[i] = transS[i * NL_ + j];
        float sc = stS[j] + emS[j];
        for (int t = 1; t < len; t++) {
            float emv = emS[t * NL_ + j];
            float a[NL_];
#pragma unroll
            for (int i = 0; i < NL_; i++) a[i] = __shfl(sc, i, 64) + Tc[i];
            float m = a[0];
#pragma unroll
            for (int i = 1; i < NL_; i++) m = fmaxf(m, a[i]);
            float sum = 0.f;
#pragma unroll
            for (int i = 0; i < NL_; i++) sum += exp2f((a[i] - m) * L2E);
            sc = emv + m + LN2 * log2f(sum);
        }
        float v = sc + enS[j];
        float mm = -1e30f, av[NL_];
#pragma unroll
        for (int i = 0; i < NL_; i++) { float vi = __shfl(v, i, 64); av[i] = vi; mm = fmaxf(mm, vi); }
        float ss = 0.f;
#pragma unroll
        for (int i = 0; i < NL_; i++) ss += exp2f((av[i] - mm) * L2E);
        if (tid == 0) {
            int l0 = lab[b * S_];
            int ll = lab[b * S_ + len - 1];
            float num = red[0] + stS[l0] + emS[l0] + enS[ll];
            partial[b] = (mm + LN2 * log2f(ss)) - num;
        }
    }
}

__global__ __launch_bounds__(128)
void reduce_kernel(const float* __restrict__ partial, float* __restrict__ out)
{
    __shared__ float s[128];
    int tid = threadIdx.x;
    s[tid] = partial[tid];
    __syncthreads();
    for (int off = 64; off; off >>= 1) {
        if (tid < off) s[tid] += s[tid + off];
        __syncthreads();
    }
    if (tid == 0) out[0] = s[0];
}

extern "C" void kernel_launch(void* const* d_in, const int* in_sizes, int n_in,
                              void* d_out, int out_size, void* d_ws, size_t ws_size,
                              hipStream_t stream)
{
    const int* seq = (const int*)d_in[0];
    const int* lab = (const int*)d_in[1];
    const float* emb    = (const float*)d_in[2];
    const float* w_ih_f = (const float*)d_in[3];
    const float* w_hh_f = (const float*)d_in[4];
    const float* b_ih_f = (const float*)d_in[5];
    const float* b_hh_f = (const float*)d_in[6];
    const float* w_ih_b = (const float*)d_in[7];
    const float* w_hh_b = (const float*)d_in[8];
    const float* b_ih_b = (const float*)d_in[9];
    const float* b_hh_b = (const float*)d_in[10];
    const float* w_out  = (const float*)d_in[11];
    const float* b_out  = (const float*)d_in[12];
    const float* start_t = (const float*)d_in[13];
    const float* end_t   = (const float*)d_in[14];
    const float* trans   = (const float*)d_in[15];

    char* ws = (char*)d_ws;
    const size_t em_bytes = (size_t)B_ * S_ * NL_ * sizeof(float);
    float* em_f    = (float*)ws;
    float* em_b    = (float*)(ws + em_bytes);
    float* partial = (float*)(ws + 2 * em_bytes);

    lstm_em_kernel<<<dim3(128), dim3(512), 0, stream>>>(seq, emb,
        w_ih_f, w_hh_f, b_ih_f, b_hh_f, w_ih_b, w_hh_b, b_ih_b, b_hh_b,
        w_out, em_f, em_b);
    crf_kernel<<<dim3(B_), dim3(256), 0, stream>>>(seq, lab, em_f, em_b, b_out,
        start_t, end_t, trans, partial);
    reduce_kernel<<<dim3(1), dim3(128), 0, stream>>>(partial, (float*)d_out);
}

// Round 8
// 742.863 us; speedup vs baseline: 1.2227x; 1.2227x over previous
//
#include <hip/hip_runtime.h>
#include <hip/hip_bf16.h>

#define B_   128
#define S_   512
#define H_   128
#define G_   512   // 4*H
#define EMB_ 128
#define NL_  9
#define CPW_ 2     // chains per workgroup

typedef __attribute__((ext_vector_type(8))) short bf16x8;
typedef __attribute__((ext_vector_type(4))) float f32x4;

// padded fragment slot: chunk stride 17 (16 rows + 1 pad)
#define FRAG(c, r) ((c) * 17 + (r))
// chunks: 0..15 xbuf0 | 16..31 xbuf1 | 32..47 hbuf0 | 48..63 hbuf1

// raw barrier: LDS fence only — vmem ops (prefetch loads, emission stores)
// stay in flight across it.
__device__ __forceinline__ void wg_bar() {
    asm volatile("s_waitcnt lgkmcnt(0)\n\ts_barrier" ::: "memory");
}

__device__ __forceinline__ float bfbits2f(short s) {
    unsigned int u = ((unsigned int)(unsigned short)s) << 16;
    return __builtin_bit_cast(float, u);
}
__device__ __forceinline__ short f2bf(float f) {
    unsigned int u = __builtin_bit_cast(unsigned int, f);
    u += 0x7FFFu + ((u >> 16) & 1u);
    return (short)(u >> 16);
}
__device__ __forceinline__ float sigm(float x) {
    return __builtin_amdgcn_rcpf(1.f + exp2f(-1.4426950408889634f * x));
}
__device__ __forceinline__ float tanh_(float x) {
    return 1.f - 2.f * __builtin_amdgcn_rcpf(1.f + exp2f(2.8853900817779268f * x));
}

// One LSTM step. All buffer bases compile-time constants; RXW is a named
// register (no dynamic indexing -> no scratch).
#define STEP_BODY(T, XR, XW, HR, HW, RXW)                                        \
  {                                                                              \
    const int t = (T);                                                           \
    if (wv == 7) {                                                               \
      if (t < S_ - 1) {                                                          \
        short4 s;                                                                \
        s.x = f2bf(RXW.x); s.y = f2bf(RXW.y);                                    \
        s.z = f2bf(RXW.z); s.w = f2bf(RXW.w);                                    \
        *(short4*)((short*)ldsA + FRAG((XW) + (part >> 1), xch) * 8              \
                   + (part & 1) * 4) = s;                                        \
      }                                                                          \
      if (t < S_ - 3) {                                                          \
        int tt3 = dir ? (S_ - 4 - t) : (t + 3);                                  \
        int tok = ldsSeq[xch * S_ + tt3];                                        \
        RXW = *(const float4*)(emb + (size_t)tok * EMB_ + part * 4);             \
      }                                                                          \
    }                                                                            \
    if (edo && t > 0) {                                                          \
      int ttp = dir ? (S_ - t) : (t - 1);                                        \
      bf16x8 h0 = ldsA[FRAG((HR) + esub * 2, ec)];                               \
      bf16x8 h1 = ldsA[FRAG((HR) + esub * 2 + 1, ec)];                           \
      float d = 0.f;                                                             \
      _Pragma("unroll")                                                          \
      for (int k = 0; k < 8; k++) d += bfbits2f(h0[k]) * wem[k];                 \
      _Pragma("unroll")                                                          \
      for (int k = 0; k < 8; k++) d += bfbits2f(h1[k]) * wem[8 + k];             \
      d += __shfl_down(d, 4, 8);                                                 \
      d += __shfl_down(d, 2, 8);                                                 \
      d += __shfl_down(d, 1, 8);                                                 \
      if (esub == 0)                                                             \
        emdir[((size_t)(brow0 + ec) * S_ + ttp) * NL_ + el] = d;                 \
    }                                                                            \
    bf16x8 af[8];                                                                \
    _Pragma("unroll")                                                            \
    for (int ks = 0; ks < 4; ks++) af[ks] = ldsA[FRAG((XR) + ks * 4 + quad, n16)]; \
    _Pragma("unroll")                                                            \
    for (int ks = 0; ks < 4; ks++) af[4 + ks] = ldsA[FRAG((HR) + ks * 4 + quad, n16)]; \
    f32x4 acc[4];                                                                \
    _Pragma("unroll")                                                            \
    for (int nt = 0; nt < 4; nt++) { f32x4 z = {0.f, 0.f, 0.f, 0.f}; acc[nt] = z; } \
    _Pragma("unroll")                                                            \
    for (int ks = 0; ks < 8; ks++)                                               \
      _Pragma("unroll")                                                          \
      for (int nt = 0; nt < 4; nt++)                                             \
        acc[nt] = __builtin_amdgcn_mfma_f32_16x16x32_bf16(af[ks], bfrag[nt][ks], acc[nt], 0, 0, 0); \
    if (quad == 0) {                                                             \
      float i0 = acc[0][0] + bias[0], f0 = acc[1][0] + bias[1];                  \
      float g0 = acc[2][0] + bias[2], o0 = acc[3][0] + bias[3];                  \
      c0 = sigm(f0) * c0 + sigm(i0) * tanh_(g0);                                 \
      float h0v = sigm(o0) * tanh_(c0);                                          \
      float i1 = acc[0][1] + bias[0], f1 = acc[1][1] + bias[1];                  \
      float g1 = acc[2][1] + bias[2], o1 = acc[3][1] + bias[3];                  \
      c1 = sigm(f1) * c1 + sigm(i1) * tanh_(g1);                                 \
      float h1v = sigm(o1) * tanh_(c1);                                          \
      short* hp = (short*)ldsA;                                                  \
      hp[FRAG((HW) + (upj >> 3), 0) * 8 + (upj & 7)] = f2bf(h0v);                \
      hp[FRAG((HW) + (upj >> 3), 1) * 8 + (upj & 7)] = f2bf(h1v);                \
    }                                                                            \
    wg_bar();                                                                    \
  }

__global__ __launch_bounds__(512, 2)
void lstm_em_kernel(const int* __restrict__ seq, const float* __restrict__ emb,
                    const float* __restrict__ w_ih_f, const float* __restrict__ w_hh_f,
                    const float* __restrict__ b_ih_f, const float* __restrict__ b_hh_f,
                    const float* __restrict__ w_ih_b, const float* __restrict__ w_hh_b,
                    const float* __restrict__ b_ih_b, const float* __restrict__ b_hh_b,
                    const float* __restrict__ w_out,
                    float* __restrict__ em_f, float* __restrict__ em_b)
{
    __shared__ bf16x8 ldsA[64 * 17];        // 17408 B
    __shared__ int    ldsSeq[CPW_ * S_];    // 4 KB

    const int tid  = threadIdx.x;
    const int wv   = tid >> 6;
    const int n16  = tid & 15;
    const int quad = (tid & 63) >> 4;
    const int dir  = blockIdx.x >> 6;
    const int brow0 = (blockIdx.x & 63) * CPW_;

    const float* wih = dir ? w_ih_b : w_ih_f;
    const float* whh = dir ? w_hh_b : w_hh_f;
    const float* bih = dir ? b_ih_b : b_ih_f;
    const float* bhh = dir ? b_hh_b : b_hh_f;
    float* emdir = dir ? em_b : em_f;

    // B fragments + bias, col n = wv*16 + n16 + nt*128 (nt: 0=i 1=f 2=g 3=o)
    bf16x8 bfrag[4][8];
    float  bias[4];
#pragma unroll
    for (int nt = 0; nt < 4; nt++) {
        int n = wv * 16 + n16 + nt * 128;
        bias[nt] = bih[n] + bhh[n];
#pragma unroll
        for (int ks = 0; ks < 8; ks++) {
            const float* p = (ks < 4) ? (wih + n * EMB_ + ks * 32 + quad * 8)
                                      : (whh + n * H_ + (ks - 4) * 32 + quad * 8);
            bf16x8 fr;
#pragma unroll
            for (int j = 0; j < 8; j++) fr[j] = f2bf(p[j]);
            bfrag[nt][ks] = fr;
        }
    }

    // emission lanes: waves 1-3, 8 lanes per (chain, label)
    const int eidx = tid - 64;
    const int eg = eidx >> 3, esub = eidx & 7;
    const bool edo = (tid >= 64) && (eg < 2 * NL_);
    const int ec = edo ? (eg / NL_) : 0;
    const int el = edo ? (eg % NL_) : 0;
    float wem[16];
    if (edo) {
#pragma unroll
        for (int k = 0; k < 16; k++)
            wem[k] = w_out[el * 256 + dir * 128 + esub * 16 + k];
    }

    // zero both h buffers (chunks 32..63)
    {   bf16x8 z = {0,0,0,0,0,0,0,0};
        for (int i = tid; i < 32 * 17; i += 512) ldsA[32 * 17 + i] = z;
    }
    ldsSeq[tid]       = seq[brow0 * S_ + tid];
    ldsSeq[tid + 512] = seq[(brow0 + 1) * S_ + tid];

    // wave 7: x0 -> xbuf0, x1 -> rxO, x2 -> rxE  (named regs, no indexing)
    const int xch  = (tid & 63) >> 5;
    const int part = tid & 31;
    float4 rxO = {0.f,0.f,0.f,0.f}, rxE = {0.f,0.f,0.f,0.f};
    if (wv == 7) {
        int t0 = dir ? (S_ - 1) : 0;
        int t1 = dir ? (S_ - 2) : 1;
        int t2 = dir ? (S_ - 3) : 2;
        const int* sq = seq + (brow0 + xch) * S_;
        float4 r0 = *(const float4*)(emb + (size_t)sq[t0] * EMB_ + part * 4);
        rxO       = *(const float4*)(emb + (size_t)sq[t1] * EMB_ + part * 4);
        rxE       = *(const float4*)(emb + (size_t)sq[t2] * EMB_ + part * 4);
        short4 s;
        s.x = f2bf(r0.x); s.y = f2bf(r0.y); s.z = f2bf(r0.z); s.w = f2bf(r0.w);
        *(short4*)((short*)ldsA + FRAG(part >> 1, xch) * 8 + (part & 1) * 4) = s;
    }

    float c0 = 0.f, c1 = 0.f;
    const int upj = wv * 16 + n16;
    wg_bar();

    for (int u = 0; u < S_ / 2; u++) {
        // even t: x in xbuf0, h_{t-1} in hbuf1(48), h_t -> hbuf0(32)
        STEP_BODY(2 * u,     0, 16, 48, 32, rxO)
        // odd t: x in xbuf1, h_{t-1} in hbuf0(32), h_t -> hbuf1(48)
        STEP_BODY(2 * u + 1, 16, 0, 32, 48, rxE)
    }

    // final emission: h_{S-1} (written at odd t=511) lives in chunks 48..63
    if (edo) {
        int ttp = dir ? 0 : (S_ - 1);
        bf16x8 h0 = ldsA[FRAG(48 + esub * 2, ec)];
        bf16x8 h1 = ldsA[FRAG(48 + esub * 2 + 1, ec)];
        float d = 0.f;
#pragma unroll
        for (int k = 0; k < 8; k++) d += bfbits2f(h0[k]) * wem[k];
#pragma unroll
        for (int k = 0; k < 8; k++) d += bfbits2f(h1[k]) * wem[8 + k];
        d += __shfl_down(d, 4, 8);
        d += __shfl_down(d, 2, 8);
        d += __shfl_down(d, 1, 8);
        if (esub == 0)
            emdir[((size_t)(brow0 + ec) * S_ + ttp) * NL_ + el] = d;
    }
}

// ---------------------------------------------------------------------------
// CRF with chunked parallel scan. One wg (640 thr) per batch.
// 64 groups x 9 lanes: group 0 scans the real vector over chunk 0 (t=1..63);
// group g>=1 = (chunk c=1+(g-1)/9, init i=(g-1)%9) builds row i of the
// chunk's 9x9 log-semiring operator via a one-hot scan. Masked steps are
// identity (sc unchanged) which is linear in the semiring, so the chunk
// decomposition is exact. Then 7 sequential 9x9 combines.
// ---------------------------------------------------------------------------
__global__ __launch_bounds__(640, 1)
void crf_kernel(const int* __restrict__ seq, const int* __restrict__ lab,
                const float* __restrict__ em_f, const float* __restrict__ em_b,
                const float* __restrict__ b_out,
                const float* __restrict__ start_t, const float* __restrict__ end_t,
                const float* __restrict__ trans, float* __restrict__ partial)
{
    __shared__ float emS[S_ * NL_];      // 18432 B
    __shared__ float transS[NL_ * NL_];
    __shared__ float stS[NL_], enS[NL_];
    __shared__ unsigned char maskS[S_];
    __shared__ float MS[7 * 81];         // chunk operators
    __shared__ float vS[NL_];
    __shared__ float redw[10];
    __shared__ int   redl[10];

    const int b = blockIdx.x, tid = threadIdx.x;
    const size_t base = (size_t)b * S_ * NL_;
    const float L2E = 1.4426950408889634f, LN2 = 0.6931471805599453f;

    for (int q = tid; q < S_ * NL_; q += 640)
        emS[q] = em_f[base + q] + em_b[base + q] + b_out[q % NL_];
    if (tid < NL_ * NL_) transS[tid] = trans[tid];
    if (tid < NL_) { stS[tid] = start_t[tid]; enS[tid] = end_t[tid]; }
    if (tid < S_) maskS[tid] = (seq[b * S_ + tid] != 0);
    __syncthreads();

    // numerator partials + mask count (waves 0-7; waves 8-9 contribute 0)
    float np = 0.f; int myc = 0;
    if (tid < S_) {
        myc = maskS[tid];
        if (tid >= 1 && maskS[tid]) {
            int lp = lab[b * S_ + tid - 1], lc = lab[b * S_ + tid];
            np = transS[lp * NL_ + lc] + emS[tid * NL_ + lc];
        }
    }
#pragma unroll
    for (int off = 32; off; off >>= 1) {
        np  += __shfl_down(np, off, 64);
        myc += __shfl_down(myc, off, 64);
    }
    if ((tid & 63) == 0) { redw[tid >> 6] = np; redl[tid >> 6] = myc; }

    // ---- chunk scans ----
    const int w = tid >> 6, l = tid & 63;
    const int lg = l / 9;                // 0..7 (l==63 -> 7 = inactive)
    const int g  = w * 7 + lg;
    const bool sact = (lg < 7) && (g < 64);
    const int jj = sact ? (l - lg * 9) : 0;
    const int gb = sact ? lg * 9 : 0;
    float Tc[NL_];
#pragma unroll
    for (int i = 0; i < NL_; i++) Tc[i] = transS[i * NL_ + jj];
    float sc; int tbeg, tend, cN = 0, iN = 0;
    if (sact && g == 0) {
        sc = stS[jj] + emS[jj];
        tbeg = 1; tend = 64;
    } else if (sact) {
        cN = 1 + (g - 1) / 9; iN = (g - 1) % 9;
        sc = (jj == iN) ? 0.f : -1e30f;
        tbeg = cN * 64; tend = tbeg + 64;
    } else {
        sc = -1e30f; tbeg = 448; tend = 512;
    }
    for (int t = tbeg; t < tend; t++) {
        float emv = emS[t * NL_ + jj];
        float a[NL_];
#pragma unroll
        for (int i = 0; i < NL_; i++) a[i] = __shfl(sc, gb + i, 64) + Tc[i];
        float m = a[0];
#pragma unroll
        for (int i = 1; i < NL_; i++) m = fmaxf(m, a[i]);
        float sum = 0.f;
#pragma unroll
        for (int i = 0; i < NL_; i++) sum += exp2f((a[i] - m) * L2E);
        float nxt = emv + m + LN2 * log2f(sum);
        sc = maskS[t] ? nxt : sc;
    }
    if (sact) {
        if (g == 0) vS[jj] = sc;
        else MS[(cN - 1) * 81 + iN * NL_ + jj] = sc;
    }
    __syncthreads();

    // ---- combine (wave 0) ----
    if (tid < 64) {
        const int j = (tid < NL_) ? tid : (NL_ - 1);
        float v = vS[j];
        for (int c = 1; c < 8; c++) {
            float a[NL_];
#pragma unroll
            for (int i = 0; i < NL_; i++)
                a[i] = __shfl(v, i, 64) + MS[(c - 1) * 81 + i * NL_ + j];
            float m = a[0];
#pragma unroll
            for (int i = 1; i < NL_; i++) m = fmaxf(m, a[i]);
            float sum = 0.f;
#pragma unroll
            for (int i = 0; i < NL_; i++) sum += exp2f((a[i] - m) * L2E);
            v = m + LN2 * log2f(sum);
        }
        v += enS[j];
        float mm = -1e30f, av[NL_];
#pragma unroll
        for (int i = 0; i < NL_; i++) { float vi = __shfl(v, i, 64); av[i] = vi; mm = fmaxf(mm, vi); }
        float ss = 0.f;
#pragma unroll
        for (int i = 0; i < NL_; i++) ss += exp2f((av[i] - mm) * L2E);
        if (tid == 0) {
            float num = 0.f; int len = 0;
#pragma unroll
            for (int ww = 0; ww < 10; ww++) { num += redw[ww]; len += redl[ww]; }
            int l0 = lab[b * S_];
            int ll = lab[b * S_ + len - 1];
            num += stS[l0] + emS[l0] + enS[ll];
            partial[b] = (mm + LN2 * log2f(ss)) - num;
        }
    }
}

__global__ __launch_bounds__(128)
void reduce_kernel(const float* __restrict__ partial, float* __restrict__ out)
{
    __shared__ float s[128];
    int tid = threadIdx.x;
    s[tid] = partial[tid];
    __syncthreads();
    for (int off = 64; off; off >>= 1) {
        if (tid < off) s[tid] += s[tid + off];
        __syncthreads();
    }
    if (tid == 0) out[0] = s[0];
}

extern "C" void kernel_launch(void* const* d_in, const int* in_sizes, int n_in,
                              void* d_out, int out_size, void* d_ws, size_t ws_size,
                              hipStream_t stream)
{
    const int* seq = (const int*)d_in[0];
    const int* lab = (const int*)d_in[1];
    const float* emb    = (const float*)d_in[2];
    const float* w_ih_f = (const float*)d_in[3];
    const float* w_hh_f = (const float*)d_in[4];
    const float* b_ih_f = (const float*)d_in[5];
    const float* b_hh_f = (const float*)d_in[6];
    const float* w_ih_b = (const float*)d_in[7];
    const float* w_hh_b = (const float*)d_in[8];
    const float* b_ih_b = (const float*)d_in[9];
    const float* b_hh_b = (const float*)d_in[10];
    const float* w_out  = (const float*)d_in[11];
    const float* b_out  = (const float*)d_in[12];
    const float* start_t = (const float*)d_in[13];
    const float* end_t   = (const float*)d_in[14];
    const float* trans   = (const float*)d_in[15];

    char* ws = (char*)d_ws;
    const size_t em_bytes = (size_t)B_ * S_ * NL_ * sizeof(float);
    float* em_f    = (float*)ws;
    float* em_b    = (float*)(ws + em_bytes);
    float* partial = (float*)(ws + 2 * em_bytes);

    lstm_em_kernel<<<dim3(128), dim3(512), 0, stream>>>(seq, emb,
        w_ih_f, w_hh_f, b_ih_f, b_hh_f, w_ih_b, w_hh_b, b_ih_b, b_hh_b,
        w_out, em_f, em_b);
    crf_kernel<<<dim3(B_), dim3(640), 0, stream>>>(seq, lab, em_f, em_b, b_out,
        start_t, end_t, trans, partial);
    reduce_kernel<<<dim3(1), dim3(128), 0, stream>>>(partial, (float*)d_out);
}

// Round 9
// 672.702 us; speedup vs baseline: 1.3502x; 1.1043x over previous
//
#include <hip/hip_runtime.h>
#include <hip/hip_bf16.h>

#define B_   128
#define S_   512
#define H_   128
#define G_   512   // 4*H
#define EMB_ 128
#define NL_  9
#define CPW_ 2     // chains per workgroup

typedef __attribute__((ext_vector_type(8))) short bf16x8;
typedef __attribute__((ext_vector_type(4))) float f32x4;

// padded fragment slot: chunk stride 17 (16 rows + 1 pad)
#define FRAG(c, r) ((c) * 17 + (r))
// chunks: 0..15 xbuf0 | 16..31 xbuf1 | 32..47 h

// raw barrier: LDS fence only — vmem ops (emb prefetch loads, emission
// stores) stay in flight across it. This is the R5->R9 fix: __syncthreads'
// vmcnt(0) drain put ~500-900 cy of L3 emb latency on every barrier.
__device__ __forceinline__ void wg_bar() {
    asm volatile("s_waitcnt lgkmcnt(0)\n\ts_barrier" ::: "memory");
}

__device__ __forceinline__ float bfbits2f(short s) {
    unsigned int u = ((unsigned int)(unsigned short)s) << 16;
    return __builtin_bit_cast(float, u);
}
__device__ __forceinline__ short f2bf(float f) {
    unsigned int u = __builtin_bit_cast(unsigned int, f);
    u += 0x7FFFu + ((u >> 16) & 1u);
    return (short)(u >> 16);
}
__device__ __forceinline__ float sigm(float x) {
    return __builtin_amdgcn_rcpf(1.f + exp2f(-1.4426950408889634f * x));
}
__device__ __forceinline__ float tanh_(float x) {
    return 1.f - 2.f * __builtin_amdgcn_rcpf(1.f + exp2f(2.8853900817779268f * x));
}

// One LSTM step, R5 phase structure, compile-time buffer bases, named
// prefetch register RXW (no dynamic reg indexing -> no scratch).
#define STEP_BODY(T, XR, XW, RXW)                                                \
  {                                                                              \
    const int t = (T);                                                           \
    /* P1: wave 0 stages x_{t+1} and refills RXW with x_{t+3} */                 \
    if (wv == 0) {                                                               \
      if (t < S_ - 1) {                                                          \
        short4 s;                                                                \
        s.x = f2bf(RXW.x); s.y = f2bf(RXW.y);                                    \
        s.z = f2bf(RXW.z); s.w = f2bf(RXW.w);                                    \
        *(short4*)((short*)ldsA + FRAG((XW) + (part >> 1), xch) * 8              \
                   + (part & 1) * 4) = s;                                        \
      }                                                                          \
      if (t < S_ - 3) {                                                          \
        int tt3 = dir ? (S_ - 4 - t) : (t + 3);                                  \
        int tok = ldsSeq[xch * S_ + tt3];                                        \
        RXW = *(const float4*)(emb + (size_t)tok * EMB_ + part * 4);             \
      }                                                                          \
    }                                                                            \
    /* P1: waves 1-3 emit em for h_{t-1} (fire-and-forget store) */              \
    if (edo && t > 0) {                                                          \
      int ttp = dir ? (S_ - t) : (t - 1);                                        \
      bf16x8 h0 = ldsA[FRAG(32 + esub * 2, ec)];                                 \
      bf16x8 h1 = ldsA[FRAG(32 + esub * 2 + 1, ec)];                             \
      float d = 0.f;                                                             \
      _Pragma("unroll")                                                          \
      for (int k = 0; k < 8; k++) d += bfbits2f(h0[k]) * wem[k];                 \
      _Pragma("unroll")                                                          \
      for (int k = 0; k < 8; k++) d += bfbits2f(h1[k]) * wem[8 + k];             \
      d += __shfl_down(d, 4, 8);                                                 \
      d += __shfl_down(d, 2, 8);                                                 \
      d += __shfl_down(d, 1, 8);                                                 \
      if (esub == 0)                                                             \
        emdir[((size_t)(brow0 + ec) * S_ + ttp) * NL_ + el] = d;                 \
    }                                                                            \
    /* P1: MFMA gates = [x_t | h_{t-1}] @ Wcat^T */                              \
    {                                                                            \
      bf16x8 af[8];                                                              \
      _Pragma("unroll")                                                          \
      for (int ks = 0; ks < 4; ks++) af[ks] = ldsA[FRAG((XR) + ks * 4 + quad, n16)]; \
      _Pragma("unroll")                                                          \
      for (int ks = 0; ks < 4; ks++) af[4 + ks] = ldsA[FRAG(32 + ks * 4 + quad, n16)]; \
      f32x4 acc0 = {0.f, 0.f, 0.f, 0.f};                                         \
      f32x4 acc1 = acc0, acc2 = acc0, acc3 = acc0;                               \
      _Pragma("unroll")                                                          \
      for (int ks = 0; ks < 8; ks++) {                                           \
        acc0 = __builtin_amdgcn_mfma_f32_16x16x32_bf16(af[ks], bfrag[0][ks], acc0, 0, 0, 0); \
        acc1 = __builtin_amdgcn_mfma_f32_16x16x32_bf16(af[ks], bfrag[1][ks], acc1, 0, 0, 0); \
        acc2 = __builtin_amdgcn_mfma_f32_16x16x32_bf16(af[ks], bfrag[2][ks], acc2, 0, 0, 0); \
        acc3 = __builtin_amdgcn_mfma_f32_16x16x32_bf16(af[ks], bfrag[3][ks], acc3, 0, 0, 0); \
      }                                                                          \
      if (quad == 0) {                                                           \
        int col = wv * 64 + n16;                                                 \
        gatesL[col]           = acc0[0]; gatesL[G_ + col]           = acc0[1];   \
        gatesL[col + 16]      = acc1[0]; gatesL[G_ + col + 16]      = acc1[1];   \
        gatesL[col + 32]      = acc2[0]; gatesL[G_ + col + 32]      = acc2[1];   \
        gatesL[col + 48]      = acc3[0]; gatesL[G_ + col + 48]      = acc3[1];   \
      }                                                                          \
    }                                                                            \
    wg_bar();                                                                    \
    /* P2: 256 threads, full 64-lane waves: nonlinearity + h -> LDS */           \
    if (tid < CPW_ * H_) {                                                       \
      float ip = gatesL[uc * G_ + uj]          + bsum[uj];                       \
      float fp = gatesL[uc * G_ + H_ + uj]     + bsum[H_ + uj];                  \
      float gp = gatesL[uc * G_ + 2 * H_ + uj] + bsum[2 * H_ + uj];              \
      float op = gatesL[uc * G_ + 3 * H_ + uj] + bsum[3 * H_ + uj];              \
      cst = sigm(fp) * cst + sigm(ip) * tanh_(gp);                               \
      float hv = sigm(op) * tanh_(cst);                                          \
      ((short*)ldsA)[FRAG(32 + (uj >> 3), uc) * 8 + (uj & 7)] = f2bf(hv);        \
    }                                                                            \
    wg_bar();                                                                    \
  }

__global__ __launch_bounds__(512, 1)
void lstm_em_kernel(const int* __restrict__ seq, const float* __restrict__ emb,
                    const float* __restrict__ w_ih_f, const float* __restrict__ w_hh_f,
                    const float* __restrict__ b_ih_f, const float* __restrict__ b_hh_f,
                    const float* __restrict__ w_ih_b, const float* __restrict__ w_hh_b,
                    const float* __restrict__ b_ih_b, const float* __restrict__ b_hh_b,
                    const float* __restrict__ w_out,
                    float* __restrict__ em_f, float* __restrict__ em_b)
{
    __shared__ bf16x8 ldsA[48 * 17];        // 13056 B
    __shared__ float  gatesL[CPW_ * G_];    // 4 KB [chain][col]
    __shared__ float  bsum[G_];             // 2 KB
    __shared__ int    ldsSeq[CPW_ * S_];    // 4 KB

    const int tid  = threadIdx.x;
    const int wv   = tid >> 6;
    const int n16  = tid & 15;
    const int quad = (tid & 63) >> 4;
    const int dir  = blockIdx.x >> 6;
    const int brow0 = (blockIdx.x & 63) * CPW_;

    const float* wih = dir ? w_ih_b : w_ih_f;
    const float* whh = dir ? w_hh_b : w_hh_f;
    const float* bih = dir ? b_ih_b : b_ih_f;
    const float* bhh = dir ? b_hh_b : b_hh_f;
    float* emdir = dir ? em_b : em_f;

    // B fragments: wave wv owns gate columns [wv*64, wv*64+64). f32 -> bf16.
    bf16x8 bfrag[4][8];
    const int nb = wv * 64 + n16;
#pragma unroll
    for (int nt = 0; nt < 4; nt++) {
        int n = nb + nt * 16;
#pragma unroll
        for (int ks = 0; ks < 8; ks++) {
            const float* p = (ks < 4) ? (wih + n * EMB_ + ks * 32 + quad * 8)
                                      : (whh + n * H_ + (ks - 4) * 32 + quad * 8);
            bf16x8 fr;
#pragma unroll
            for (int j = 0; j < 8; j++) fr[j] = f2bf(p[j]);
            bfrag[nt][ks] = fr;
        }
    }

    // emission lanes: waves 1-3, 8 lanes per (chain, label)
    const int eidx = tid - 64;
    const int eg = eidx >> 3, esub = eidx & 7;
    const bool edo = (tid >= 64) && (eg < 2 * NL_);
    const int ec = edo ? (eg / NL_) : 0;
    const int el = edo ? (eg % NL_) : 0;
    float wem[16];
    if (edo) {
#pragma unroll
        for (int k = 0; k < 16; k++)
            wem[k] = w_out[el * 256 + dir * 128 + esub * 16 + k];
    }

    bsum[tid] = bih[tid] + bhh[tid];
    // zero h chunks (32..47)
    if (tid < 16 * 17) { bf16x8 z = {0,0,0,0,0,0,0,0}; ldsA[32 * 17 + tid] = z; }
    ldsSeq[tid]       = seq[brow0 * S_ + tid];
    ldsSeq[tid + 512] = seq[(brow0 + 1) * S_ + tid];

    // wave 0: x0 -> xbuf0, x1 -> rxO, x2 -> rxE (named regs)
    const int xch  = (tid & 63) >> 5;
    const int part = tid & 31;
    float4 rxO = {0.f,0.f,0.f,0.f}, rxE = {0.f,0.f,0.f,0.f};
    if (wv == 0) {
        int t0 = dir ? (S_ - 1) : 0;
        int t1 = dir ? (S_ - 2) : 1;
        int t2 = dir ? (S_ - 3) : 2;
        const int* sq = seq + (brow0 + xch) * S_;
        float4 r0 = *(const float4*)(emb + (size_t)sq[t0] * EMB_ + part * 4);
        rxO       = *(const float4*)(emb + (size_t)sq[t1] * EMB_ + part * 4);
        rxE       = *(const float4*)(emb + (size_t)sq[t2] * EMB_ + part * 4);
        short4 s;
        s.x = f2bf(r0.x); s.y = f2bf(r0.y); s.z = f2bf(r0.z); s.w = f2bf(r0.w);
        *(short4*)((short*)ldsA + FRAG(part >> 1, xch) * 8 + (part & 1) * 4) = s;
    }

    float cst = 0.f;
    const int uc = tid >> 7;     // P2: chain (tid<256)
    const int uj = tid & 127;
    wg_bar();

    for (int u = 0; u < S_ / 2; u++) {
        STEP_BODY(2 * u,     0, 16, rxO)   // even: x in xbuf0, write x_{t+1} -> xbuf1
        STEP_BODY(2 * u + 1, 16, 0, rxE)   // odd:  x in xbuf1, write -> xbuf0
    }

    // final emission (h_{S-1})
    if (edo) {
        int ttp = dir ? 0 : (S_ - 1);
        bf16x8 h0 = ldsA[FRAG(32 + esub * 2, ec)];
        bf16x8 h1 = ldsA[FRAG(32 + esub * 2 + 1, ec)];
        float d = 0.f;
#pragma unroll
        for (int k = 0; k < 8; k++) d += bfbits2f(h0[k]) * wem[k];
#pragma unroll
        for (int k = 0; k < 8; k++) d += bfbits2f(h1[k]) * wem[8 + k];
        d += __shfl_down(d, 4, 8);
        d += __shfl_down(d, 2, 8);
        d += __shfl_down(d, 1, 8);
        if (esub == 0)
            emdir[((size_t)(brow0 + ec) * S_ + ttp) * NL_ + el] = d;
    }
}

// ---------------------------------------------------------------------------
// CRF with chunked parallel scan (unchanged from R8 — verified correct).
// ---------------------------------------------------------------------------
__global__ __launch_bounds__(640, 1)
void crf_kernel(const int* __restrict__ seq, const int* __restrict__ lab,
                const float* __restrict__ em_f, const float* __restrict__ em_b,
                const float* __restrict__ b_out,
                const float* __restrict__ start_t, const float* __restrict__ end_t,
                const float* __restrict__ trans, float* __restrict__ partial)
{
    __shared__ float emS[S_ * NL_];
    __shared__ float transS[NL_ * NL_];
    __shared__ float stS[NL_], enS[NL_];
    __shared__ unsigned char maskS[S_];
    __shared__ float MS[7 * 81];
    __shared__ float vS[NL_];
    __shared__ float redw[10];
    __shared__ int   redl[10];

    const int b = blockIdx.x, tid = threadIdx.x;
    const size_t base = (size_t)b * S_ * NL_;
    const float L2E = 1.4426950408889634f, LN2 = 0.6931471805599453f;

    for (int q = tid; q < S_ * NL_; q += 640)
        emS[q] = em_f[base + q] + em_b[base + q] + b_out[q % NL_];
    if (tid < NL_ * NL_) transS[tid] = trans[tid];
    if (tid < NL_) { stS[tid] = start_t[tid]; enS[tid] = end_t[tid]; }
    if (tid < S_) maskS[tid] = (seq[b * S_ + tid] != 0);
    __syncthreads();

    float np = 0.f; int myc = 0;
    if (tid < S_) {
        myc = maskS[tid];
        if (tid >= 1 && maskS[tid]) {
            int lp = lab[b * S_ + tid - 1], lc = lab[b * S_ + tid];
            np = transS[lp * NL_ + lc] + emS[tid * NL_ + lc];
        }
    }
#pragma unroll
    for (int off = 32; off; off >>= 1) {
        np  += __shfl_down(np, off, 64);
        myc += __shfl_down(myc, off, 64);
    }
    if ((tid & 63) == 0) { redw[tid >> 6] = np; redl[tid >> 6] = myc; }

    const int w = tid >> 6, l = tid & 63;
    const int lg = l / 9;
    const int g  = w * 7 + lg;
    const bool sact = (lg < 7) && (g < 64);
    const int jj = sact ? (l - lg * 9) : 0;
    const int gb = sact ? lg * 9 : 0;
    float Tc[NL_];
#pragma unroll
    for (int i = 0; i < NL_; i++) Tc[i] = transS[i * NL_ + jj];
    float sc; int tbeg, tend, cN = 0, iN = 0;
    if (sact && g == 0) {
        sc = stS[jj] + emS[jj];
        tbeg = 1; tend = 64;
    } else if (sact) {
        cN = 1 + (g - 1) / 9; iN = (g - 1) % 9;
        sc = (jj == iN) ? 0.f : -1e30f;
        tbeg = cN * 64; tend = tbeg + 64;
    } else {
        sc = -1e30f; tbeg = 448; tend = 512;
    }
    for (int t = tbeg; t < tend; t++) {
        float emv = emS[t * NL_ + jj];
        float a[NL_];
#pragma unroll
        for (int i = 0; i < NL_; i++) a[i] = __shfl(sc, gb + i, 64) + Tc[i];
        float m = a[0];
#pragma unroll
        for (int i = 1; i < NL_; i++) m = fmaxf(m, a[i]);
        float sum = 0.f;
#pragma unroll
        for (int i = 0; i < NL_; i++) sum += exp2f((a[i] - m) * L2E);
        float nxt = emv + m + LN2 * log2f(sum);
        sc = maskS[t] ? nxt : sc;
    }
    if (sact) {
        if (g == 0) vS[jj] = sc;
        else MS[(cN - 1) * 81 + iN * NL_ + jj] = sc;
    }
    __syncthreads();

    if (tid < 64) {
        const int j = (tid < NL_) ? tid : (NL_ - 1);
        float v = vS[j];
        for (int c = 1; c < 8; c++) {
            float a[NL_];
#pragma unroll
            for (int i = 0; i < NL_; i++)
                a[i] = __shfl(v, i, 64) + MS[(c - 1) * 81 + i * NL_ + j];
            float m = a[0];
#pragma unroll
            for (int i = 1; i < NL_; i++) m = fmaxf(m, a[i]);
            float sum = 0.f;
#pragma unroll
            for (int i = 0; i < NL_; i++) sum += exp2f((a[i] - m) * L2E);
            v = m + LN2 * log2f(sum);
        }
        v += enS[j];
        float mm = -1e30f, av[NL_];
#pragma unroll
        for (int i = 0; i < NL_; i++) { float vi = __shfl(v, i, 64); av[i] = vi; mm = fmaxf(mm, vi); }
        float ss = 0.f;
#pragma unroll
        for (int i = 0; i < NL_; i++) ss += exp2f((av[i] - mm) * L2E);
        if (tid == 0) {
            float num = 0.f; int len = 0;
#pragma unroll
            for (int ww = 0; ww < 10; ww++) { num += redw[ww]; len += redl[ww]; }
            int l0 = lab[b * S_];
            int ll = lab[b * S_ + len - 1];
            num += stS[l0] + emS[l0] + enS[ll];
            partial[b] = (mm + LN2 * log2f(ss)) - num;
        }
    }
}

__global__ __launch_bounds__(128)
void reduce_kernel(const float* __restrict__ partial, float* __restrict__ out)
{
    __shared__ float s[128];
    int tid = threadIdx.x;
    s[tid] = partial[tid];
    __syncthreads();
    for (int off = 64; off; off >>= 1) {
        if (tid < off) s[tid] += s[tid + off];
        __syncthreads();
    }
    if (tid == 0) out[0] = s[0];
}

extern "C" void kernel_launch(void* const* d_in, const int* in_sizes, int n_in,
                              void* d_out, int out_size, void* d_ws, size_t ws_size,
                              hipStream_t stream)
{
    const int* seq = (const int*)d_in[0];
    const int* lab = (const int*)d_in[1];
    const float* emb    = (const float*)d_in[2];
    const float* w_ih_f = (const float*)d_in[3];
    const float* w_hh_f = (const float*)d_in[4];
    const float* b_ih_f = (const float*)d_in[5];
    const float* b_hh_f = (const float*)d_in[6];
    const float* w_ih_b = (const float*)d_in[7];
    const float* w_hh_b = (const float*)d_in[8];
    const float* b_ih_b = (const float*)d_in[9];
    const float* b_hh_b = (const float*)d_in[10];
    const float* w_out  = (const float*)d_in[11];
    const float* b_out  = (const float*)d_in[12];
    const float* start_t = (const float*)d_in[13];
    const float* end_t   = (const float*)d_in[14];
    const float* trans   = (const float*)d_in[15];

    char* ws = (char*)d_ws;
    const size_t em_bytes = (size_t)B_ * S_ * NL_ * sizeof(float);
    float* em_f    = (float*)ws;
    float* em_b    = (float*)(ws + em_bytes);
    float* partial = (float*)(ws + 2 * em_bytes);

    lstm_em_kernel<<<dim3(128), dim3(512), 0, stream>>>(seq, emb,
        w_ih_f, w_hh_f, b_ih_f, b_hh_f, w_ih_b, w_hh_b, b_ih_b, b_hh_b,
        w_out, em_f, em_b);
    crf_kernel<<<dim3(B_), dim3(640), 0, stream>>>(seq, lab, em_f, em_b, b_out,
        start_t, end_t, trans, partial);
    reduce_kernel<<<dim3(1), dim3(128), 0, stream>>>(partial, (float*)d_out);
}